// Round 1
// 4155.667 us; speedup vs baseline: 1.0292x; 1.0292x over previous
//
#include <hip/hip_runtime.h>
#include <hip/hip_bf16.h>
#include <math.h>

typedef __hip_bfloat16 bf16;
typedef __attribute__((ext_vector_type(8))) short short8;
typedef __attribute__((ext_vector_type(4))) short short4v;
typedef __attribute__((ext_vector_type(4))) float f32x4;

// problem dims
#define B_    64
#define T_    512
#define D_    128
#define N_    510
#define H_    512
#define TOK_  384
#define PRED1_ 12533760L  // B_*N_*TOK_
#define TOKOFF_ 37601280L // 3*PRED1_ : tokens offset in d_out (floats)

// ---- workspace layout (bytes) ----
#define O_XBF  0UL            // x bf16            8,388,608
#define O_SWB  8388608UL      // sess_W bf16         524,288
#define O_PW   8912896UL      // proj_W bf16         393,216
#define O_WIH  9306112UL      // gru_Wih bf16      1,572,864
#define O_WHH  10878976UL     // gru_Whh bf16      1,572,864
#define O_W1   12451840UL     // head_W1 bf16      1,572,864
#define O_W2   14024704UL     // head_W2 bf16      1,179,648
#define O_TOK  15204352UL     // tokens bf16      25,067,520  rows [n*64+b]
#define O_HBF  40271872UL     // h bf16 (post-RMS)33,423,360
#define O_HID  73695232UL     // hidden bf16      33,423,360  rows [s*64+b]
#define O_ABF  107118592UL    // gelu act bf16 (first 4KB doubles as GRU flags)
#define O_GX   140541952UL    // gx bf16 100,270,080 (h_pre fp32 overlapped first)

// ---------------- fp32 -> bf16 convert ----------------
__global__ void k_f2b(const float* __restrict__ s, bf16* __restrict__ d, int n4) {
  int i = blockIdx.x * 256 + threadIdx.x;
  if (i < n4) {
    float4 v = ((const float4*)s)[i];
    union { short4v sv; bf16 h[4]; } u;
    u.h[0] = __float2bfloat16(v.x); u.h[1] = __float2bfloat16(v.y);
    u.h[2] = __float2bfloat16(v.z); u.h[3] = __float2bfloat16(v.w);
    ((short4v*)d)[i] = u.sv;
  }
}

// ---------------- generic bf16 MFMA GEMM: C = A[M,K] @ W[N,K]^T + bias ----------------
enum { EPI_F32 = 0, EPI_BF16 = 1, EPI_GELU = 2, EPI_TOK = 3, EPI_F32R = 4 };
#define SLDA 40

template <int EPI>
__global__ __launch_bounds__(256, 2) void k_gemm(
    const bf16* __restrict__ A, const bf16* __restrict__ W,
    const float* __restrict__ bias, void* __restrict__ C,
    int K, int ldc, long zA, long zW, long zB, long zC,
    const int* __restrict__ sidx, float* __restrict__ tokf, bf16* __restrict__ tokb)
{
  const int tid = threadIdx.x;
  const int bm = blockIdx.x, bn = blockIdx.y, z = blockIdx.z;
  const int wsel = (EPI == EPI_TOK) ? sidx[z] : z;
  const int lane = tid & 63, wave = tid >> 6;
  const int wm = (wave & 1) << 6, wn = (wave >> 1) << 6;
  const int r16 = lane & 15, quad = lane >> 4;

  __shared__ bf16 sA[128 * SLDA];
  __shared__ bf16 sB[128 * SLDA];

  const bf16* Ag = A + (long)z * zA + (long)bm * 128 * K;
  const bf16* Wg = W + (long)wsel * zW + (long)bn * 128 * K;

  f32x4 zf = {0.f, 0.f, 0.f, 0.f};
  f32x4 acc[4][4];
  for (int i = 0; i < 4; ++i) for (int j = 0; j < 4; ++j) acc[i][j] = zf;

  const int sr = tid >> 1, sc = (tid & 1) << 4;
  for (int k0 = 0; k0 < K; k0 += 32) {
    *(short8*)&sA[sr*SLDA + sc]     = *(const short8*)&Ag[(long)sr*K + k0 + sc];
    *(short8*)&sA[sr*SLDA + sc + 8] = *(const short8*)&Ag[(long)sr*K + k0 + sc + 8];
    *(short8*)&sB[sr*SLDA + sc]     = *(const short8*)&Wg[(long)sr*K + k0 + sc];
    *(short8*)&sB[sr*SLDA + sc + 8] = *(const short8*)&Wg[(long)sr*K + k0 + sc + 8];
    __syncthreads();
    short8 fa[4], fb[4];
    for (int i = 0; i < 4; ++i) fa[i] = *(const short8*)&sA[(wm + i*16 + r16)*SLDA + quad*8];
    for (int j = 0; j < 4; ++j) fb[j] = *(const short8*)&sB[(wn + j*16 + r16)*SLDA + quad*8];
    for (int i = 0; i < 4; ++i)
      for (int j = 0; j < 4; ++j)
        acc[i][j] = __builtin_amdgcn_mfma_f32_16x16x32_bf16(fa[i], fb[j], acc[i][j], 0, 0, 0);
    __syncthreads();
  }

  const float* bz = bias + (long)wsel * zB + bn * 128;
  for (int i = 0; i < 4; ++i) {
    for (int j = 0; j < 4; ++j) {
      const int colL = wn + j*16 + r16;
      const float bv = bz[colL];
      for (int r = 0; r < 4; ++r) {
        float v = acc[i][j][r] + bv;
        const long grow = (long)bm*128 + wm + i*16 + quad*4 + r;
        const long gcol = (long)bn*128 + colL;
        if (EPI == EPI_F32) {
          ((float*)C)[(long)z*zC + grow*ldc + gcol] = v;
        } else if (EPI == EPI_BF16) {
          ((bf16*)C)[(long)z*zC + grow*ldc + gcol] = __float2bfloat16(v);
        } else if (EPI == EPI_GELU) {
          v = 0.5f * v * (1.0f + erff(v * 0.70710678118654752f));
          ((bf16*)C)[(long)z*zC + grow*ldc + gcol] = __float2bfloat16(v);
        } else if (EPI == EPI_F32R) {
          // rows are [n*64+b]; output wants [b*510+n]
          const long rb = grow & 63, rn = grow >> 6;
          ((float*)C)[(rb*510 + rn)*ldc + gcol] = v;
        } else { // EPI_TOK: z=batch, grow=t, gcol=e
          for (int p = 0; p < 3; ++p) {
            long n = grow - p;
            if (n >= 0 && n < N_) {
              tokf[((long)z*N_ + n)*TOK_ + gcol*3 + p] = v;                 // d_out: [b][n][tok]
              tokb[((long)n*B_ + z)*TOK_ + gcol*3 + p] = __float2bfloat16(v); // ws: rows [n*64+b]
            }
          }
        }
      }
    }
  }
}

// ---------------- RMSNorm rows of 512: fp32 in -> bf16 out ----------------
__global__ __launch_bounds__(256) void k_rms(const float* __restrict__ hpre,
                                             const float* __restrict__ scale,
                                             bf16* __restrict__ hbf)
{
  const int wave = threadIdx.x >> 6, lane = threadIdx.x & 63;
  const long row = (long)blockIdx.x * 4 + wave;
  const float* p = hpre + row * 512 + lane * 8;
  float4 v0 = *(const float4*)p;
  float4 v1 = *(const float4*)(p + 4);
  float ss = v0.x*v0.x + v0.y*v0.y + v0.z*v0.z + v0.w*v0.w
           + v1.x*v1.x + v1.y*v1.y + v1.z*v1.z + v1.w*v1.w;
  for (int m = 32; m >= 1; m >>= 1) ss += __shfl_xor(ss, m, 64);
  const float inv = 1.0f / sqrtf(ss * (1.0f/512.0f) + 1e-6f);
  const float* sc = scale + lane * 8;
  union { short8 sv; bf16 h[8]; } u;
  u.h[0] = __float2bfloat16(v0.x*inv*sc[0]); u.h[1] = __float2bfloat16(v0.y*inv*sc[1]);
  u.h[2] = __float2bfloat16(v0.z*inv*sc[2]); u.h[3] = __float2bfloat16(v0.w*inv*sc[3]);
  u.h[4] = __float2bfloat16(v1.x*inv*sc[4]); u.h[5] = __float2bfloat16(v1.y*inv*sc[5]);
  u.h[6] = __float2bfloat16(v1.z*inv*sc[6]); u.h[7] = __float2bfloat16(v1.w*inv*sc[7]);
  *(short8*)(hbf + row * 512 + lane * 8) = u.sv;
}

// ---------------- GRU: persistent kernel, fence-free device-scope sync ----------------
// 32 WGs x 192 thr. WG w owns hpos [16w,16w+16). wave g in {0=r,1=z,2=n}.
// Whh frags persistent in VGPRs. hidden layout [s][b][512]; gx layout [s][b][1536].
// Sync redesign: hidden[s] is written with device-scope (sc1, write-through) dword
// stores; producer orders with a raw s_waitcnt vmcnt(0) + relaxed agent flag store;
// consumers poll relaxed agent flags and stage via global_load_lds with CPol sc1
// (device scope, reads through L1/L2 from the coherence point). This removes ALL
// per-step buffer_wbl2 / buffer_inv cache walks (32 of each per step before).
#define KP 520   // LDS row pad (elems): 1040B rows -> b128 reads 2-way (free-ish)

// aux=16 == CPol SC1 on gfx950: device-scope load, bypasses (possibly stale) L1/L2
#define GL2LDS(g, l) __builtin_amdgcn_global_load_lds( \
    (const __attribute__((address_space(1))) void*)(g), \
    (__attribute__((address_space(3))) void*)(l), 16, 0, 16)

__global__ __launch_bounds__(192, 1) void k_gru(
    const bf16* __restrict__ gx,   // [s][b][1536] bf16 (bih already added)
    const bf16* __restrict__ Whh,  // [1536][512] bf16
    const float* __restrict__ bhh, // [1536]
    bf16* __restrict__ hidden,     // [s][b][512] bf16
    int* __restrict__ flags)       // 32 flags, 32 ints apart (128B lines)
{
  const int tid = threadIdx.x;
  const int g = tid / 64;           // gate: 0=r 1=z 2=n
  const int lane = tid & 63;
  const int c16 = lane & 15, quad = lane >> 4;
  const int hw = blockIdx.x * 16;   // hpos base

  __shared__ bf16 hp[64 * KP];      // h_prev [b][k] padded: 66,560 B
  __shared__ float ex[2][64 * 16];  // r,z exchange: 8,192 B

  // persistent weight fragments: B-frag row n = g*512 + hw + c16, k = kt*32 + quad*8
  short8 wf[16];
  {
    const bf16* wrow = Whh + (long)(g*512 + hw + c16) * 512;
    for (int kt = 0; kt < 16; ++kt) wf[kt] = *(const short8*)&wrow[kt*32 + quad*8];
  }
  const float bh = bhh[g*512 + hw + c16];

  { // zero hp (h0 = 0)
    short8 z8 = {0,0,0,0,0,0,0,0};
    for (int c = tid; c < 64*KP/8; c += 192) *(short8*)&hp[c*8] = z8;
  }
  __syncthreads();

  int* myflag = &flags[blockIdx.x * 32];
  const int pidx = (lane & 31) * 32;

  // prefetch gx for s=0: lane owns (b = mt*16+quad*4+i2, col = g*512+hw+c16)
  float gxv[16], gxn[16];
  {
    const bf16* gxs = gx + (long)0 + g*512 + hw + c16;
    for (int mt = 0; mt < 4; ++mt)
      for (int i2 = 0; i2 < 4; ++i2)
        gxv[mt*4+i2] = __bfloat162float(gxs[(long)(mt*16 + quad*4 + i2) * 1536]);
  }

  for (int s = 0; s < 510; ++s) {
    // ---- prefetch gx for s+1 FIRST: HBM latency hides under the flag wait ----
    {
      const int s1 = (s < 509) ? s + 1 : 509;
      const bf16* gxs = gx + (long)s1*64*1536 + g*512 + hw + c16;
      for (int mt = 0; mt < 4; ++mt)
        for (int i2 = 0; i2 < 4; ++i2)
          gxn[mt*4+i2] = __bfloat162float(gxs[(long)(mt*16 + quad*4 + i2) * 1536]);
    }
    if (s > 0) {
      // ---- wait: all WGs produced hidden[s-1] (relaxed agent loads, no fence) ----
      while (true) {
        int v = __hip_atomic_load(&flags[pidx], __ATOMIC_RELAXED, __HIP_MEMORY_SCOPE_AGENT);
        if (__all(v >= s)) break;
        __builtin_amdgcn_s_sleep(1);
      }
      asm volatile("" ::: "memory");  // compiler ordering: staging after poll
      // ---- stage hidden[s-1] -> hp via device-scope global_load_lds ----
      // data was written through to L3 (sc1 stores); sc1 loads read it there.
      const bf16* src = hidden + (long)(s-1)*64*512 + lane*8;
      for (int b = g; b < 64; b += 3) {
        GL2LDS(src + b*512, &hp[b*KP]);
      }
    }
    __syncthreads();   // hp staged (waits the global_load_lds vmcnt)

    f32x4 zf = {0.f,0.f,0.f,0.f};
    f32x4 acc[4]; for (int mt = 0; mt < 4; ++mt) acc[mt] = zf;
    for (int mt = 0; mt < 4; ++mt)
      for (int kt = 0; kt < 16; ++kt) {
        short8 a = *(const short8*)&hp[(mt*16 + c16)*KP + kt*32 + quad*8];
        acc[mt] = __builtin_amdgcn_mfma_f32_16x16x32_bf16(a, wf[kt], acc[mt], 0, 0, 0);
      }

    if (g < 2) {  // r and z: sigmoid(gx + gh + bhh), publish to LDS
      for (int mt = 0; mt < 4; ++mt)
        for (int i2 = 0; i2 < 4; ++i2) {
          float pre = gxv[mt*4+i2] + acc[mt][i2] + bh;
          ex[g][(mt*16 + quad*4 + i2)*16 + c16] = 1.0f / (1.0f + expf(-pre));
        }
    }
    __syncthreads();
    if (g == 2) {  // n-gate wave finishes the step and publishes
      for (int mt = 0; mt < 4; ++mt)
        for (int i2 = 0; i2 < 4; ++i2) {
          const int br = mt*16 + quad*4 + i2;
          const float rr = ex[0][br*16 + c16];
          const float zz = ex[1][br*16 + c16];
          const float nn = tanhf(gxv[mt*4+i2] + rr * (acc[mt][i2] + bh));
          const float hpv = __bfloat162float(hp[br*KP + hw + c16]);
          const float hn = (1.0f - zz)*nn + zz*hpv;
          // pack 2 bf16 cols into one dword (lanes c16 even/odd pair via shfl),
          // store device-scope (write-through past L2 -> visible at L3)
          union { bf16 h; unsigned short u; } cb; cb.h = __float2bfloat16(hn);
          unsigned int mine = cb.u;
          unsigned int part = (unsigned int)__shfl_xor((int)mine, 1, 64);
          if (!(c16 & 1)) {
            unsigned int w = (part << 16) | mine;  // lo = col c16, hi = col c16+1
            __hip_atomic_store((unsigned int*)(hidden + ((long)s*64 + br)*512 + hw + c16),
                               w, __ATOMIC_RELAXED, __HIP_MEMORY_SCOPE_AGENT);
          }
        }
      // order: all device-scope data stores acked at coherence point, then flag.
      // NO buffer_wbl2 (nothing dirty in L2 from this kernel), NO fence builtin.
      asm volatile("s_waitcnt vmcnt(0)" ::: "memory");
      if (lane == 0)
        __hip_atomic_store(myflag, s + 1, __ATOMIC_RELAXED, __HIP_MEMORY_SCOPE_AGENT);
    }
    for (int i = 0; i < 16; ++i) gxv[i] = gxn[i];
  }
}

// ---------------- launch ----------------
extern "C" void kernel_launch(void* const* d_in, const int* in_sizes, int n_in,
                              void* d_out, int out_size, void* d_ws, size_t ws_size,
                              hipStream_t stream)
{
  const float* x    = (const float*)d_in[0];
  const int*   sidx = (const int*)d_in[1];
  const float* sW   = (const float*)d_in[2];
  const float* sb   = (const float*)d_in[3];
  const float* pW   = (const float*)d_in[4];
  const float* pb   = (const float*)d_in[5];
  const float* rsc  = (const float*)d_in[6];
  const float* wih  = (const float*)d_in[7];
  const float* whh  = (const float*)d_in[8];
  const float* bih  = (const float*)d_in[9];
  const float* bhh  = (const float*)d_in[10];
  const float* w1   = (const float*)d_in[11];
  const float* b1   = (const float*)d_in[12];
  const float* w2   = (const float*)d_in[13];
  const float* b2   = (const float*)d_in[14];
  char* ws = (char*)d_ws;
  float* out = (float*)d_out;

  bf16* xbf   = (bf16*)(ws + O_XBF);
  bf16* swbf  = (bf16*)(ws + O_SWB);
  bf16* pwbf  = (bf16*)(ws + O_PW);
  bf16* wihbf = (bf16*)(ws + O_WIH);
  bf16* whhbf = (bf16*)(ws + O_WHH);
  bf16* w1bf  = (bf16*)(ws + O_W1);
  bf16* w2bf  = (bf16*)(ws + O_W2);
  bf16* tokbf = (bf16*)(ws + O_TOK);
  bf16* hbf   = (bf16*)(ws + O_HBF);
  bf16* hidbf = (bf16*)(ws + O_HID);
  bf16* abf   = (bf16*)(ws + O_ABF);
  int*  bar   = (int*)(ws + O_ABF);   // flags live in abf (dead during GRU)
  float* hpre = (float*)(ws + O_GX);  // fp32 h_pre overlaps gx region
  bf16* gxbf  = (bf16*)(ws + O_GX);

  auto cvt = [&](const float* s, bf16* dp, long n) {
    int n4 = (int)(n >> 2);
    k_f2b<<<dim3((n4 + 255) / 256), dim3(256), 0, stream>>>(s, dp, n4);
  };
  cvt(x,   xbf,   (long)B_*T_*D_);
  cvt(sW,  swbf,  16L*128*128);
  cvt(pW,  pwbf,  512L*384);
  cvt(wih, wihbf, 1536L*512);
  cvt(whh, whhbf, 1536L*512);
  cvt(w1,  w1bf,  3L*512*512);
  cvt(w2,  w2bf,  3L*384*512);

  // 1) session align -> tokens (fp32 to d_out [b][n][tok], bf16 to ws rows [n*64+b])
  k_gemm<EPI_TOK><<<dim3(4, 1, 64), dim3(256), 0, stream>>>(
      xbf, swbf, sb, nullptr, 128, 0,
      (long)T_*D_, 128L*128, 128L, 0L, sidx, out + TOKOFF_, tokbf);

  // 2) proj: h_pre = tokens @ proj_W^T + b  (fp32, rows [n*64+b])
  k_gemm<EPI_F32><<<dim3(255, 4, 1), dim3(256), 0, stream>>>(
      tokbf, pwbf, pb, hpre, 384, 512, 0, 0, 0, 0, nullptr, nullptr, nullptr);

  // 3) RMSNorm -> h bf16
  k_rms<<<dim3(8160), dim3(256), 0, stream>>>(hpre, rsc, hbf);

  // 4) gx = h @ Wih^T + bih  (bf16, rows [n*64+b] == [s][b][1536])
  k_gemm<EPI_BF16><<<dim3(255, 12, 1), dim3(256), 0, stream>>>(
      hbf, wihbf, bih, gxbf, 512, 1536, 0, 0, 0, 0, nullptr, nullptr, nullptr);

  // 5) GRU scan (flags zeroed first; abf region is dead until heads)
  hipMemsetAsync(ws + O_ABF, 0, 4096, stream);
  k_gru<<<dim3(32), dim3(192), 0, stream>>>(gxbf, whhbf, bhh, hidbf, bar);

  // 6) heads: a = gelu(hidden @ W1^T + b1); preds = a @ W2^T + b2 (remap rows)
  for (int k = 0; k < 3; ++k) {
    k_gemm<EPI_GELU><<<dim3(255, 4, 1), dim3(256), 0, stream>>>(
        hidbf, w1bf + (long)k*512*512, b1 + (long)k*512, abf,
        512, 512, 0, 0, 0, 0, nullptr, nullptr, nullptr);
    k_gemm<EPI_F32R><<<dim3(255, 3, 1), dim3(256), 0, stream>>>(
        abf, w2bf + (long)k*384*512, b2 + (long)k*384, out + (long)k*PRED1_,
        512, 384, 0, 0, 0, 0, nullptr, nullptr, nullptr);
  }
}

// Round 2
// 2120.938 us; speedup vs baseline: 2.0165x; 1.9594x over previous
//
#include <hip/hip_runtime.h>
#include <hip/hip_bf16.h>
#include <math.h>

typedef __hip_bfloat16 bf16;
typedef __attribute__((ext_vector_type(8))) short short8;
typedef __attribute__((ext_vector_type(4))) short short4v;
typedef __attribute__((ext_vector_type(4))) float f32x4;

// problem dims
#define B_    64
#define T_    512
#define D_    128
#define N_    510
#define H_    512
#define TOK_  384
#define PRED1_ 12533760L  // B_*N_*TOK_
#define TOKOFF_ 37601280L // 3*PRED1_ : tokens offset in d_out (floats)

// ---- workspace layout (bytes) ----
#define O_XBF  0UL            // x bf16            8,388,608
#define O_SWB  8388608UL      // sess_W bf16         524,288
#define O_PW   8912896UL      // proj_W bf16         393,216
#define O_WIH  9306112UL      // gru_Wih bf16      1,572,864
#define O_WHH  10878976UL     // gru_Whh bf16      1,572,864
#define O_W1   12451840UL     // head_W1 bf16      1,572,864
#define O_W2   14024704UL     // head_W2 bf16      1,179,648
#define O_TOK  15204352UL     // tokens bf16      25,067,520  rows [n*64+b]
#define O_HBF  40271872UL     // h bf16 (post-RMS)33,423,360
#define O_HID  73695232UL     // hidden bf16      33,423,360  rows [s*64+b]
#define O_ABF  107118592UL    // gelu act bf16 (first 32KB doubles as GRU flags)
#define O_GX   140541952UL    // gx bf16 100,270,080 (h_pre fp32 overlapped first)

// ---------------- fp32 -> bf16 convert ----------------
__global__ void k_f2b(const float* __restrict__ s, bf16* __restrict__ d, int n4) {
  int i = blockIdx.x * 256 + threadIdx.x;
  if (i < n4) {
    float4 v = ((const float4*)s)[i];
    union { short4v sv; bf16 h[4]; } u;
    u.h[0] = __float2bfloat16(v.x); u.h[1] = __float2bfloat16(v.y);
    u.h[2] = __float2bfloat16(v.z); u.h[3] = __float2bfloat16(v.w);
    ((short4v*)d)[i] = u.sv;
  }
}

// ---------------- generic bf16 MFMA GEMM: C = A[M,K] @ W[N,K]^T + bias ----------------
enum { EPI_F32 = 0, EPI_BF16 = 1, EPI_GELU = 2, EPI_TOK = 3, EPI_F32R = 4 };
#define SLDA 40

template <int EPI>
__global__ __launch_bounds__(256, 2) void k_gemm(
    const bf16* __restrict__ A, const bf16* __restrict__ W,
    const float* __restrict__ bias, void* __restrict__ C,
    int K, int ldc, long zA, long zW, long zB, long zC,
    const int* __restrict__ sidx, float* __restrict__ tokf, bf16* __restrict__ tokb)
{
  const int tid = threadIdx.x;
  const int bm = blockIdx.x, bn = blockIdx.y, z = blockIdx.z;
  const int wsel = (EPI == EPI_TOK) ? sidx[z] : z;
  const int lane = tid & 63, wave = tid >> 6;
  const int wm = (wave & 1) << 6, wn = (wave >> 1) << 6;
  const int r16 = lane & 15, quad = lane >> 4;

  __shared__ bf16 sA[128 * SLDA];
  __shared__ bf16 sB[128 * SLDA];

  const bf16* Ag = A + (long)z * zA + (long)bm * 128 * K;
  const bf16* Wg = W + (long)wsel * zW + (long)bn * 128 * K;

  f32x4 zf = {0.f, 0.f, 0.f, 0.f};
  f32x4 acc[4][4];
  for (int i = 0; i < 4; ++i) for (int j = 0; j < 4; ++j) acc[i][j] = zf;

  const int sr = tid >> 1, sc = (tid & 1) << 4;
  for (int k0 = 0; k0 < K; k0 += 32) {
    *(short8*)&sA[sr*SLDA + sc]     = *(const short8*)&Ag[(long)sr*K + k0 + sc];
    *(short8*)&sA[sr*SLDA + sc + 8] = *(const short8*)&Ag[(long)sr*K + k0 + sc + 8];
    *(short8*)&sB[sr*SLDA + sc]     = *(const short8*)&Wg[(long)sr*K + k0 + sc];
    *(short8*)&sB[sr*SLDA + sc + 8] = *(const short8*)&Wg[(long)sr*K + k0 + sc + 8];
    __syncthreads();
    short8 fa[4], fb[4];
    for (int i = 0; i < 4; ++i) fa[i] = *(const short8*)&sA[(wm + i*16 + r16)*SLDA + quad*8];
    for (int j = 0; j < 4; ++j) fb[j] = *(const short8*)&sB[(wn + j*16 + r16)*SLDA + quad*8];
    for (int i = 0; i < 4; ++i)
      for (int j = 0; j < 4; ++j)
        acc[i][j] = __builtin_amdgcn_mfma_f32_16x16x32_bf16(fa[i], fb[j], acc[i][j], 0, 0, 0);
    __syncthreads();
  }

  const float* bz = bias + (long)wsel * zB + bn * 128;
  for (int i = 0; i < 4; ++i) {
    for (int j = 0; j < 4; ++j) {
      const int colL = wn + j*16 + r16;
      const float bv = bz[colL];
      for (int r = 0; r < 4; ++r) {
        float v = acc[i][j][r] + bv;
        const long grow = (long)bm*128 + wm + i*16 + quad*4 + r;
        const long gcol = (long)bn*128 + colL;
        if (EPI == EPI_F32) {
          ((float*)C)[(long)z*zC + grow*ldc + gcol] = v;
        } else if (EPI == EPI_BF16) {
          ((bf16*)C)[(long)z*zC + grow*ldc + gcol] = __float2bfloat16(v);
        } else if (EPI == EPI_GELU) {
          v = 0.5f * v * (1.0f + erff(v * 0.70710678118654752f));
          ((bf16*)C)[(long)z*zC + grow*ldc + gcol] = __float2bfloat16(v);
        } else if (EPI == EPI_F32R) {
          // rows are [n*64+b]; output wants [b*510+n]
          const long rb = grow & 63, rn = grow >> 6;
          ((float*)C)[(rb*510 + rn)*ldc + gcol] = v;
        } else { // EPI_TOK: z=batch, grow=t, gcol=e
          for (int p = 0; p < 3; ++p) {
            long n = grow - p;
            if (n >= 0 && n < N_) {
              tokf[((long)z*N_ + n)*TOK_ + gcol*3 + p] = v;                 // d_out: [b][n][tok]
              tokb[((long)n*B_ + z)*TOK_ + gcol*3 + p] = __float2bfloat16(v); // ws: rows [n*64+b]
            }
          }
        }
      }
    }
  }
}

// ---------------- RMSNorm rows of 512: fp32 in -> bf16 out ----------------
__global__ __launch_bounds__(256) void k_rms(const float* __restrict__ hpre,
                                             const float* __restrict__ scale,
                                             bf16* __restrict__ hbf)
{
  const int wave = threadIdx.x >> 6, lane = threadIdx.x & 63;
  const long row = (long)blockIdx.x * 4 + wave;
  const float* p = hpre + row * 512 + lane * 8;
  float4 v0 = *(const float4*)p;
  float4 v1 = *(const float4*)(p + 4);
  float ss = v0.x*v0.x + v0.y*v0.y + v0.z*v0.z + v0.w*v0.w
           + v1.x*v1.x + v1.y*v1.y + v1.z*v1.z + v1.w*v1.w;
  for (int m = 32; m >= 1; m >>= 1) ss += __shfl_xor(ss, m, 64);
  const float inv = 1.0f / sqrtf(ss * (1.0f/512.0f) + 1e-6f);
  const float* sc = scale + lane * 8;
  union { short8 sv; bf16 h[8]; } u;
  u.h[0] = __float2bfloat16(v0.x*inv*sc[0]); u.h[1] = __float2bfloat16(v0.y*inv*sc[1]);
  u.h[2] = __float2bfloat16(v0.z*inv*sc[2]); u.h[3] = __float2bfloat16(v0.w*inv*sc[3]);
  u.h[4] = __float2bfloat16(v1.x*inv*sc[4]); u.h[5] = __float2bfloat16(v1.y*inv*sc[5]);
  u.h[6] = __float2bfloat16(v1.z*inv*sc[6]); u.h[7] = __float2bfloat16(v1.w*inv*sc[7]);
  *(short8*)(hbf + row * 512 + lane * 8) = u.sv;
}

// ---------------- GRU: batch-split persistent scan ----------------
// The GRU recurrence is independent per batch row. Split into 8 independent
// batch-groups of 8 batches; each group has its OWN 32 column-chunk WGs and
// OWN flag set, free-running (no cross-group sync). Grid = 256 WGs (1/CU).
// Per-WG per-step work is 8x smaller than the 32-WG version: stage 8KB (not
// 64KB), 16 MFMA/wave (not 64), 4 gx regs (not 16), 4 hn/lane tail.
// WG (gb,cw): batches [8gb,8gb+8), h-cols [16cw,16cw+16). wave g in {0=r,1=z,2=n}.
#define KP 520   // LDS row pad (elems)

// aux=16 == CPol SC1 on gfx950: device-scope load (coherent past L2)
#define GL2LDS(g, l) __builtin_amdgcn_global_load_lds( \
    (const __attribute__((address_space(1))) void*)(g), \
    (__attribute__((address_space(3))) void*)(l), 16, 0, 16)

__global__ __launch_bounds__(192, 1) void k_gru(
    const bf16* __restrict__ gx,   // [s][b][1536] bf16 (bih already added)
    const bf16* __restrict__ Whh,  // [1536][512] bf16
    const float* __restrict__ bhh, // [1536]
    bf16* __restrict__ hidden,     // [s][b][512] bf16
    int* __restrict__ flags)       // 256 flags, 32 ints apart (128B lines)
{
  const int tid = threadIdx.x;
  const int g = tid / 64;           // gate: 0=r 1=z 2=n
  const int lane = tid & 63;
  const int c16 = lane & 15, quad = lane >> 4;
  const int cw = blockIdx.x & 31;   // column chunk
  const int gb = blockIdx.x >> 5;   // batch group
  const int hw = cw * 16;           // hpos base
  const int b0 = gb * 8;            // batch base

  __shared__ bf16 hp[16 * KP];      // h_prev rows (8 valid + 8 zero-pad): 16,640 B
  __shared__ float ex[2][16 * 16];  // r,z exchange: 2,048 B

  // persistent weight fragments: B-frag row n = g*512 + hw + c16, k = kt*32 + quad*8
  short8 wf[16];
  {
    const bf16* wrow = Whh + (long)(g*512 + hw + c16) * 512;
    for (int kt = 0; kt < 16; ++kt) wf[kt] = *(const short8*)&wrow[kt*32 + quad*8];
  }
  const float bh = bhh[g*512 + hw + c16];

  { // zero hp (h0 = 0; rows 8..15 stay zero forever = MFMA pad)
    short8 z8 = {0,0,0,0,0,0,0,0};
    for (int c = tid; c < 16*KP/8; c += 192) *(short8*)&hp[c*8] = z8;
  }
  __syncthreads();

  int* myflag = &flags[(gb*32 + cw) * 32];
  const int pidx = (gb*32 + (lane & 31)) * 32;

  // gx fetch rows: lane owns batch rows br = quad*4+i2 (valid quad<2);
  // quads 2,3 mirror quads 0,1 so addresses stay in-bounds (values unused).
  const int brv = (quad & 1) * 4;

  float gxv[4], gxn[4];
  {
    const bf16* gxs = gx + (long)b0 * 1536 + g*512 + hw + c16;
    for (int i2 = 0; i2 < 4; ++i2)
      gxv[i2] = __bfloat162float(gxs[(long)(brv + i2) * 1536]);
  }

  for (int s = 0; s < 510; ++s) {
    // prefetch gx for s+1 FIRST: HBM latency hides under the flag wait
    {
      const int s1 = (s < 509) ? s + 1 : 509;
      const bf16* gxs = gx + ((long)s1*64 + b0)*1536 + g*512 + hw + c16;
      for (int i2 = 0; i2 < 4; ++i2)
        gxn[i2] = __bfloat162float(gxs[(long)(brv + i2) * 1536]);
    }
    if (s > 0) {
      // wait: all 32 WGs of THIS group produced hidden[s-1] for these batches
      while (true) {
        int v = __hip_atomic_load(&flags[pidx], __ATOMIC_RELAXED, __HIP_MEMORY_SCOPE_AGENT);
        if (__all(v >= s)) break;
        __builtin_amdgcn_s_sleep(1);
      }
      asm volatile("" ::: "memory");  // compiler ordering: staging after poll
      // stage hidden[s-1] rows b0..b0+7 -> hp (device-scope global_load_lds)
      const bf16* src = hidden + ((long)(s-1)*64 + b0)*512 + lane*8;
      for (int b = g; b < 8; b += 3) {
        GL2LDS(src + b*512, &hp[b*KP]);
      }
    }
    __syncthreads();   // hp staged (waits the global_load_lds vmcnt)

    f32x4 acc = {0.f,0.f,0.f,0.f};
    for (int kt = 0; kt < 16; ++kt) {
      short8 a = *(const short8*)&hp[c16*KP + kt*32 + quad*8];
      acc = __builtin_amdgcn_mfma_f32_16x16x32_bf16(a, wf[kt], acc, 0, 0, 0);
    }

    if (g < 2) {  // r and z: sigmoid(gx + gh + bhh), publish to LDS
      for (int i2 = 0; i2 < 4; ++i2) {
        float pre = gxv[i2] + acc[i2] + bh;
        ex[g][(quad*4 + i2)*16 + c16] = 1.0f / (1.0f + expf(-pre));
      }
    }
    __syncthreads();
    if (g == 2) {  // n-gate wave finishes the step and publishes
      if (quad < 2) {
        for (int i2 = 0; i2 < 4; ++i2) {
          const int br = quad*4 + i2;
          const float rr = ex[0][br*16 + c16];
          const float zz = ex[1][br*16 + c16];
          const float nn = tanhf(gxv[i2] + rr * (acc[i2] + bh));
          const float hpv = __bfloat162float(hp[br*KP + hw + c16]);
          const float hn = (1.0f - zz)*nn + zz*hpv;
          // pack 2 bf16 cols into one dword; device-scope write-through store
          union { bf16 h; unsigned short u; } cb; cb.h = __float2bfloat16(hn);
          unsigned int mine = cb.u;
          unsigned int part = (unsigned int)__shfl_xor((int)mine, 1, 64);
          if (!(c16 & 1)) {
            unsigned int w = (part << 16) | mine;
            __hip_atomic_store((unsigned int*)(hidden + ((long)s*64 + b0 + br)*512 + hw + c16),
                               w, __ATOMIC_RELAXED, __HIP_MEMORY_SCOPE_AGENT);
          }
        }
      }
      if (s < 509) {  // last step: no consumer, let stores drain at kernel end
        asm volatile("s_waitcnt vmcnt(0)" ::: "memory");
        if (lane == 0)
          __hip_atomic_store(myflag, s + 1, __ATOMIC_RELAXED, __HIP_MEMORY_SCOPE_AGENT);
      }
    }
    for (int i = 0; i < 4; ++i) gxv[i] = gxn[i];
  }
}

// ---------------- launch ----------------
extern "C" void kernel_launch(void* const* d_in, const int* in_sizes, int n_in,
                              void* d_out, int out_size, void* d_ws, size_t ws_size,
                              hipStream_t stream)
{
  const float* x    = (const float*)d_in[0];
  const int*   sidx = (const int*)d_in[1];
  const float* sW   = (const float*)d_in[2];
  const float* sb   = (const float*)d_in[3];
  const float* pW   = (const float*)d_in[4];
  const float* pb   = (const float*)d_in[5];
  const float* rsc  = (const float*)d_in[6];
  const float* wih  = (const float*)d_in[7];
  const float* whh  = (const float*)d_in[8];
  const float* bih  = (const float*)d_in[9];
  const float* bhh  = (const float*)d_in[10];
  const float* w1   = (const float*)d_in[11];
  const float* b1   = (const float*)d_in[12];
  const float* w2   = (const float*)d_in[13];
  const float* b2   = (const float*)d_in[14];
  char* ws = (char*)d_ws;
  float* out = (float*)d_out;

  bf16* xbf   = (bf16*)(ws + O_XBF);
  bf16* swbf  = (bf16*)(ws + O_SWB);
  bf16* pwbf  = (bf16*)(ws + O_PW);
  bf16* wihbf = (bf16*)(ws + O_WIH);
  bf16* whhbf = (bf16*)(ws + O_WHH);
  bf16* w1bf  = (bf16*)(ws + O_W1);
  bf16* w2bf  = (bf16*)(ws + O_W2);
  bf16* tokbf = (bf16*)(ws + O_TOK);
  bf16* hbf   = (bf16*)(ws + O_HBF);
  bf16* hidbf = (bf16*)(ws + O_HID);
  bf16* abf   = (bf16*)(ws + O_ABF);
  int*  bar   = (int*)(ws + O_ABF);   // flags live in abf (dead during GRU)
  float* hpre = (float*)(ws + O_GX);  // fp32 h_pre overlaps gx region
  bf16* gxbf  = (bf16*)(ws + O_GX);

  auto cvt = [&](const float* s, bf16* dp, long n) {
    int n4 = (int)(n >> 2);
    k_f2b<<<dim3((n4 + 255) / 256), dim3(256), 0, stream>>>(s, dp, n4);
  };
  cvt(x,   xbf,   (long)B_*T_*D_);
  cvt(sW,  swbf,  16L*128*128);
  cvt(pW,  pwbf,  512L*384);
  cvt(wih, wihbf, 1536L*512);
  cvt(whh, whhbf, 1536L*512);
  cvt(w1,  w1bf,  3L*512*512);
  cvt(w2,  w2bf,  3L*384*512);

  // 1) session align -> tokens (fp32 to d_out [b][n][tok], bf16 to ws rows [n*64+b])
  k_gemm<EPI_TOK><<<dim3(4, 1, 64), dim3(256), 0, stream>>>(
      xbf, swbf, sb, nullptr, 128, 0,
      (long)T_*D_, 128L*128, 128L, 0L, sidx, out + TOKOFF_, tokbf);

  // 2) proj: h_pre = tokens @ proj_W^T + b  (fp32, rows [n*64+b])
  k_gemm<EPI_F32><<<dim3(255, 4, 1), dim3(256), 0, stream>>>(
      tokbf, pwbf, pb, hpre, 384, 512, 0, 0, 0, 0, nullptr, nullptr, nullptr);

  // 3) RMSNorm -> h bf16
  k_rms<<<dim3(8160), dim3(256), 0, stream>>>(hpre, rsc, hbf);

  // 4) gx = h @ Wih^T + bih  (bf16, rows [n*64+b] == [s][b][1536])
  k_gemm<EPI_BF16><<<dim3(255, 12, 1), dim3(256), 0, stream>>>(
      hbf, wihbf, bih, gxbf, 512, 1536, 0, 0, 0, 0, nullptr, nullptr, nullptr);

  // 5) GRU scan: 8 independent batch-groups x 32 col-chunks = 256 WGs (1/CU).
  //    Flags: 256 x 128B = 32KB, zeroed first (abf region is dead until heads).
  hipMemsetAsync(ws + O_ABF, 0, 32768, stream);
  k_gru<<<dim3(256), dim3(192), 0, stream>>>(gxbf, whhbf, bhh, hidbf, bar);

  // 6) heads: a = gelu(hidden @ W1^T + b1); preds = a @ W2^T + b2 (remap rows)
  for (int k = 0; k < 3; ++k) {
    k_gemm<EPI_GELU><<<dim3(255, 4, 1), dim3(256), 0, stream>>>(
        hidbf, w1bf + (long)k*512*512, b1 + (long)k*512, abf,
        512, 512, 0, 0, 0, 0, nullptr, nullptr, nullptr);
    k_gemm<EPI_F32R><<<dim3(255, 3, 1), dim3(256), 0, stream>>>(
        abf, w2bf + (long)k*384*512, b2 + (long)k*384, out + (long)k*PRED1_,
        512, 384, 0, 0, 0, 0, nullptr, nullptr, nullptr);
  }
}